// Round 1
// baseline (493.082 us; speedup 1.0000x reference)
//
#include <hip/hip_runtime.h>
#include <math.h>

#define EPS 1e-5f

constexpr int B = 32, C = 64, H = 128, W = 128;
constexpr int HW = H * W;            // 16384 pairs per (b,c) plane
constexpr int NSAMP = B * HW;        // 524288 samples per channel
constexpr int PLANE_FLOATS = HW * 2; // 32768 floats per (b,c) plane
constexpr int PLANE_F4 = PLANE_FLOATS / 4; // 8192 float4 per plane

// ws layout: per channel 8 floats (5 used): [S0, S1, S00, S01, S11, pad, pad, pad]
// Pass 1: per-(b,c)-plane partial sums -> atomicAdd into per-channel accumulators.
__global__ __launch_bounds__(256) void reduce_kernel(const float* __restrict__ z,
                                                     float* __restrict__ sums) {
    const int blk = blockIdx.x;          // b*C + c
    const int c = blk % C;
    const float4* p = (const float4*)(z + (size_t)blk * PLANE_FLOATS);

    float s0 = 0.f, s1 = 0.f, s00 = 0.f, s01 = 0.f, s11 = 0.f;
    for (int i = threadIdx.x; i < PLANE_F4; i += 256) {
        float4 v = p[i];                 // (z0, z1, z0', z1')
        s0  += v.x + v.z;
        s1  += v.y + v.w;
        s00 += v.x * v.x + v.z * v.z;
        s11 += v.y * v.y + v.w * v.w;
        s01 += v.x * v.y + v.z * v.w;
    }

    // wave-64 shuffle reduce
    #pragma unroll
    for (int o = 32; o > 0; o >>= 1) {
        s0  += __shfl_down(s0,  o, 64);
        s1  += __shfl_down(s1,  o, 64);
        s00 += __shfl_down(s00, o, 64);
        s01 += __shfl_down(s01, o, 64);
        s11 += __shfl_down(s11, o, 64);
    }

    __shared__ float sm[5][4];
    const int lane = threadIdx.x & 63;
    const int wv = threadIdx.x >> 6;
    if (lane == 0) {
        sm[0][wv] = s0; sm[1][wv] = s1; sm[2][wv] = s00; sm[3][wv] = s01; sm[4][wv] = s11;
    }
    __syncthreads();
    if (threadIdx.x == 0) {
        float t0 = 0.f, t1 = 0.f, t2 = 0.f, t3 = 0.f, t4 = 0.f;
        #pragma unroll
        for (int w = 0; w < 4; w++) {
            t0 += sm[0][w]; t1 += sm[1][w]; t2 += sm[2][w]; t3 += sm[3][w]; t4 += sm[4][w];
        }
        atomicAdd(&sums[c * 8 + 0], t0);
        atomicAdd(&sums[c * 8 + 1], t1);
        atomicAdd(&sums[c * 8 + 2], t2);
        atomicAdd(&sums[c * 8 + 3], t3);
        atomicAdd(&sums[c * 8 + 4], t4);
    }
}

// Pass 2: per-channel affine derived from sums, applied elementwise.
__global__ __launch_bounds__(256) void apply_kernel(const float* __restrict__ z,
                                                    const float* __restrict__ sums,
                                                    const float* __restrict__ gamma,
                                                    const float* __restrict__ beta,
                                                    float* __restrict__ out) {
    const int blk = blockIdx.x;          // b*C + c
    const int c = blk % C;

    __shared__ float tr[6];              // A00, A01, A10, A11, b0, b1
    if (threadIdx.x == 0) {
        const float S0  = sums[c * 8 + 0];
        const float S1  = sums[c * 8 + 1];
        const float S00 = sums[c * 8 + 2];
        const float S01 = sums[c * 8 + 3];
        const float S11 = sums[c * 8 + 4];
        const float invN = 1.0f / (float)NSAMP;
        const float mu0 = S0 * invN;
        const float mu1 = S1 * invN;
        // covariance + EPS*I
        const float a  = S00 * invN - mu0 * mu0 + EPS;
        const float bc = S01 * invN - mu0 * mu1;   // b == c (symmetric)
        const float d  = S11 * invN - mu1 * mu1 + EPS;
        // inverse principal sqrt of [[a,bc],[bc,d]]
        const float s = sqrtf(a * d - bc * bc);
        const float t = sqrtf(a + d + 2.0f * s);
        const float sa = (a + s) / t;
        const float sb = bc / t;
        const float sc = bc / t;
        const float sd = (d + s) / t;
        const float inv_det = 1.0f / (sa * sd - sb * sc);
        const float w00 =  sd * inv_det;
        const float w01 = -sb * inv_det;
        const float w10 = -sc * inv_det;
        const float w11 =  sa * inv_det;
        // fold gamma: A = gamma @ w
        const float g00 = gamma[0], g01 = gamma[1], g10 = gamma[2], g11 = gamma[3];
        const float A00 = g00 * w00 + g01 * w10;
        const float A01 = g00 * w01 + g01 * w11;
        const float A10 = g10 * w00 + g11 * w10;
        const float A11 = g10 * w01 + g11 * w11;
        tr[0] = A00; tr[1] = A01; tr[2] = A10; tr[3] = A11;
        tr[4] = beta[0] - (A00 * mu0 + A01 * mu1);
        tr[5] = beta[1] - (A10 * mu0 + A11 * mu1);
    }
    __syncthreads();
    const float A00 = tr[0], A01 = tr[1], A10 = tr[2], A11 = tr[3];
    const float b0 = tr[4], b1 = tr[5];

    const float4* p = (const float4*)(z + (size_t)blk * PLANE_FLOATS);
    float4* q = (float4*)(out + (size_t)blk * PLANE_FLOATS);
    for (int i = threadIdx.x; i < PLANE_F4; i += 256) {
        float4 v = p[i];
        float4 r;
        r.x = A00 * v.x + A01 * v.y + b0;
        r.y = A10 * v.x + A11 * v.y + b1;
        r.z = A00 * v.z + A01 * v.w + b0;
        r.w = A10 * v.z + A11 * v.w + b1;
        q[i] = r;
    }
}

extern "C" void kernel_launch(void* const* d_in, const int* in_sizes, int n_in,
                              void* d_out, int out_size, void* d_ws, size_t ws_size,
                              hipStream_t stream) {
    const float* z     = (const float*)d_in[0];
    const float* gamma = (const float*)d_in[1];
    const float* beta  = (const float*)d_in[2];
    float* out  = (float*)d_out;
    float* sums = (float*)d_ws;

    hipMemsetAsync(sums, 0, C * 8 * sizeof(float), stream);
    reduce_kernel<<<B * C, 256, 0, stream>>>(z, sums);
    apply_kernel<<<B * C, 256, 0, stream>>>(z, sums, gamma, beta, out);
}

// Round 3
// 478.734 us; speedup vs baseline: 1.0300x; 1.0300x over previous
//
#include <hip/hip_runtime.h>
#include <math.h>

#define EPS 1e-5f

constexpr int B = 32, C = 64, H = 128, W = 128;
constexpr int HW = H * W;            // 16384 pairs per (b,c) plane
constexpr int NSAMP = B * HW;        // 524288 samples per channel
constexpr int PLANE_FLOATS = HW * 2; // 32768 floats per (b,c) plane
constexpr int PLANE_F4 = PLANE_FLOATS / 4; // 8192 float4 per plane

typedef float vfloat4 __attribute__((ext_vector_type(4)));  // native vector for NT stores

// ws layout: per channel 8 floats (5 used): [S0, S1, S00, S01, S11, pad...]
// Pass 1: per-(b,c)-plane partial sums -> atomicAdd into per-channel accumulators.
// 4 independent load chains per thread for memory-level parallelism.
__global__ __launch_bounds__(256) void reduce_kernel(const float* __restrict__ z,
                                                     float* __restrict__ sums) {
    const int blk = blockIdx.x;          // b*C + c
    const int c = blk % C;
    const vfloat4* p = (const vfloat4*)(z + (size_t)blk * PLANE_FLOATS);

    float s0 = 0.f, s1 = 0.f, s00 = 0.f, s01 = 0.f, s11 = 0.f;
    // 8192 float4 / (256 threads * 4-way) = 8 outer iterations
    for (int base = 0; base < PLANE_F4; base += 1024) {
        const int i = base + threadIdx.x;
        vfloat4 v0 = p[i];
        vfloat4 v1 = p[i + 256];
        vfloat4 v2 = p[i + 512];
        vfloat4 v3 = p[i + 768];
        s0  += (v0.x + v0.z) + (v1.x + v1.z) + (v2.x + v2.z) + (v3.x + v3.z);
        s1  += (v0.y + v0.w) + (v1.y + v1.w) + (v2.y + v2.w) + (v3.y + v3.w);
        s00 += (v0.x * v0.x + v0.z * v0.z) + (v1.x * v1.x + v1.z * v1.z)
             + (v2.x * v2.x + v2.z * v2.z) + (v3.x * v3.x + v3.z * v3.z);
        s11 += (v0.y * v0.y + v0.w * v0.w) + (v1.y * v1.y + v1.w * v1.w)
             + (v2.y * v2.y + v2.w * v2.w) + (v3.y * v3.y + v3.w * v3.w);
        s01 += (v0.x * v0.y + v0.z * v0.w) + (v1.x * v1.y + v1.z * v1.w)
             + (v2.x * v2.y + v2.z * v2.w) + (v3.x * v3.y + v3.z * v3.w);
    }

    // wave-64 shuffle reduce
    #pragma unroll
    for (int o = 32; o > 0; o >>= 1) {
        s0  += __shfl_down(s0,  o, 64);
        s1  += __shfl_down(s1,  o, 64);
        s00 += __shfl_down(s00, o, 64);
        s01 += __shfl_down(s01, o, 64);
        s11 += __shfl_down(s11, o, 64);
    }

    __shared__ float sm[5][4];
    const int lane = threadIdx.x & 63;
    const int wv = threadIdx.x >> 6;
    if (lane == 0) {
        sm[0][wv] = s0; sm[1][wv] = s1; sm[2][wv] = s00; sm[3][wv] = s01; sm[4][wv] = s11;
    }
    __syncthreads();
    if (threadIdx.x == 0) {
        float t0 = 0.f, t1 = 0.f, t2 = 0.f, t3 = 0.f, t4 = 0.f;
        #pragma unroll
        for (int w = 0; w < 4; w++) {
            t0 += sm[0][w]; t1 += sm[1][w]; t2 += sm[2][w]; t3 += sm[3][w]; t4 += sm[4][w];
        }
        atomicAdd(&sums[c * 8 + 0], t0);
        atomicAdd(&sums[c * 8 + 1], t1);
        atomicAdd(&sums[c * 8 + 2], t2);
        atomicAdd(&sums[c * 8 + 3], t3);
        atomicAdd(&sums[c * 8 + 4], t4);
    }
}

// Pass 2: per-channel affine derived from sums, applied elementwise.
// 4 independent load chains; non-temporal stores so the output stream
// doesn't evict z from L3 (z re-read can hit Infinity Cache).
__global__ __launch_bounds__(256) void apply_kernel(const float* __restrict__ z,
                                                    const float* __restrict__ sums,
                                                    const float* __restrict__ gamma,
                                                    const float* __restrict__ beta,
                                                    float* __restrict__ out) {
    const int blk = blockIdx.x;          // b*C + c
    const int c = blk % C;

    __shared__ float tr[6];              // A00, A01, A10, A11, b0, b1
    if (threadIdx.x == 0) {
        const float S0  = sums[c * 8 + 0];
        const float S1  = sums[c * 8 + 1];
        const float S00 = sums[c * 8 + 2];
        const float S01 = sums[c * 8 + 3];
        const float S11 = sums[c * 8 + 4];
        const float invN = 1.0f / (float)NSAMP;
        const float mu0 = S0 * invN;
        const float mu1 = S1 * invN;
        const float a  = S00 * invN - mu0 * mu0 + EPS;
        const float bc = S01 * invN - mu0 * mu1;
        const float d  = S11 * invN - mu1 * mu1 + EPS;
        const float s = sqrtf(a * d - bc * bc);
        const float t = sqrtf(a + d + 2.0f * s);
        const float sa = (a + s) / t;
        const float sb = bc / t;
        const float sd = (d + s) / t;
        const float inv_det = 1.0f / (sa * sd - sb * sb);
        const float w00 =  sd * inv_det;
        const float w01 = -sb * inv_det;
        const float w10 = -sb * inv_det;
        const float w11 =  sa * inv_det;
        const float g00 = gamma[0], g01 = gamma[1], g10 = gamma[2], g11 = gamma[3];
        const float A00 = g00 * w00 + g01 * w10;
        const float A01 = g00 * w01 + g01 * w11;
        const float A10 = g10 * w00 + g11 * w10;
        const float A11 = g10 * w01 + g11 * w11;
        tr[0] = A00; tr[1] = A01; tr[2] = A10; tr[3] = A11;
        tr[4] = beta[0] - (A00 * mu0 + A01 * mu1);
        tr[5] = beta[1] - (A10 * mu0 + A11 * mu1);
    }
    __syncthreads();
    const float A00 = tr[0], A01 = tr[1], A10 = tr[2], A11 = tr[3];
    const float b0 = tr[4], b1 = tr[5];

    const vfloat4* p = (const vfloat4*)(z + (size_t)blk * PLANE_FLOATS);
    vfloat4* q = (vfloat4*)(out + (size_t)blk * PLANE_FLOATS);
    for (int base = 0; base < PLANE_F4; base += 1024) {
        const int i = base + threadIdx.x;
        vfloat4 v0 = p[i];
        vfloat4 v1 = p[i + 256];
        vfloat4 v2 = p[i + 512];
        vfloat4 v3 = p[i + 768];
        vfloat4 r0, r1, r2, r3;
        r0.x = A00 * v0.x + A01 * v0.y + b0;  r0.y = A10 * v0.x + A11 * v0.y + b1;
        r0.z = A00 * v0.z + A01 * v0.w + b0;  r0.w = A10 * v0.z + A11 * v0.w + b1;
        r1.x = A00 * v1.x + A01 * v1.y + b0;  r1.y = A10 * v1.x + A11 * v1.y + b1;
        r1.z = A00 * v1.z + A01 * v1.w + b0;  r1.w = A10 * v1.z + A11 * v1.w + b1;
        r2.x = A00 * v2.x + A01 * v2.y + b0;  r2.y = A10 * v2.x + A11 * v2.y + b1;
        r2.z = A00 * v2.z + A01 * v2.w + b0;  r2.w = A10 * v2.z + A11 * v2.w + b1;
        r3.x = A00 * v3.x + A01 * v3.y + b0;  r3.y = A10 * v3.x + A11 * v3.y + b1;
        r3.z = A00 * v3.z + A01 * v3.w + b0;  r3.w = A10 * v3.z + A11 * v3.w + b1;
        __builtin_nontemporal_store(r0, &q[i]);
        __builtin_nontemporal_store(r1, &q[i + 256]);
        __builtin_nontemporal_store(r2, &q[i + 512]);
        __builtin_nontemporal_store(r3, &q[i + 768]);
    }
}

extern "C" void kernel_launch(void* const* d_in, const int* in_sizes, int n_in,
                              void* d_out, int out_size, void* d_ws, size_t ws_size,
                              hipStream_t stream) {
    const float* z     = (const float*)d_in[0];
    const float* gamma = (const float*)d_in[1];
    const float* beta  = (const float*)d_in[2];
    float* out  = (float*)d_out;
    float* sums = (float*)d_ws;

    (void)hipMemsetAsync(sums, 0, C * 8 * sizeof(float), stream);
    reduce_kernel<<<B * C, 256, 0, stream>>>(z, sums);
    apply_kernel<<<B * C, 256, 0, stream>>>(z, sums, gamma, beta, out);
}